// Round 1
// baseline (316.033 us; speedup 1.0000x reference)
//
#include <hip/hip_runtime.h>
#include <stdint.h>
#include <stddef.h>

#define H  512
#define BB 64
#define TV 512
#define TT 64

typedef short s8v __attribute__((ext_vector_type(8)));   // 8 bf16 (4 VGPRs)
typedef float f4v __attribute__((ext_vector_type(4)));   // MFMA accumulator

// ---- helpers -------------------------------------------------------------

__device__ inline unsigned short f2bf(float f) {
  unsigned int u = __float_as_uint(f);
  u = (u + 0x7fffu + ((u >> 16) & 1u)) >> 16;   // RNE
  return (unsigned short)u;
}

// pack two floats to packed bf16 pair (lo in low half)
__device__ inline unsigned int pk2bf(float lo, float hi) {
  unsigned int a = __float_as_uint(lo);
  a = (a + 0x7fffu + ((a >> 16) & 1u)) >> 16;
  unsigned int b = __float_as_uint(hi);
  b = (b + 0x7fffu + ((b >> 16) & 1u)) & 0xffff0000u;
  return a | b;
}

__device__ inline float fast_tanh(float x) {
  x = fminf(15.f, fmaxf(-15.f, x));
  float e = __expf(2.f * x);
  return (e - 1.f) * __builtin_amdgcn_rcpf(e + 1.f);
}

// ---- 1) transpose + convert Wav/Wat -> bf16 [n][k] -----------------------
// grid (8,8,2) block 256
__global__ void k_prep_w(const float* __restrict__ Wav, const float* __restrict__ Wat,
                         unsigned short* __restrict__ Wavt, unsigned short* __restrict__ Watt) {
  __shared__ float tile[64][65];   // +1 pad: conflict-free transpose
  const float* src = blockIdx.z ? Wat : Wav;
  unsigned short* dst = blockIdx.z ? Watt : Wavt;
  const int k0 = blockIdx.x * 64, j0 = blockIdx.y * 64;
  const int tid = threadIdx.x;
  for (int i = 0; i < 16; ++i) {
    int e = tid + i * 256; int r = e >> 6, c = e & 63;
    tile[r][c] = src[(size_t)(k0 + r) * H + j0 + c];
  }
  __syncthreads();
  for (int i = 0; i < 16; ++i) {
    int e = tid + i * 256; int r = e >> 6, c = e & 63;
    dst[(size_t)(j0 + r) * H + k0 + c] = f2bf(tile[c][r]);
  }
}

// ---- 2) the four h-driven matmuls ---------------------------------------
// grid (64 b, 4 which) block 256. which: 0 uv(+bav) 1 ut(+bat) 2 Wbs 3 hWhh
__global__ void k_hmm(const float* __restrict__ h,
                      const float* __restrict__ Uav, const float* __restrict__ Uat,
                      const float* __restrict__ Wb,  const float* __restrict__ Whh,
                      const float* __restrict__ bav, const float* __restrict__ bat,
                      float* __restrict__ uv, float* __restrict__ ut,
                      float* __restrict__ wbs, float* __restrict__ hwhh) {
  __shared__ float hs[H];
  const int b = blockIdx.x, w = blockIdx.y, tid = threadIdx.x;
  const float* W = (w == 0) ? Uav : (w == 1) ? Uat : (w == 2) ? Wb : Whh;
  float* out     = (w == 0) ? uv  : (w == 1) ? ut  : (w == 2) ? wbs : hwhh;
  hs[tid] = h[b * H + tid];
  hs[tid + 256] = h[b * H + tid + 256];
  __syncthreads();
  float a0 = 0.f, a1 = 0.f;
  if (w == 0) { a0 = bav[tid]; a1 = bav[tid + 256]; }
  else if (w == 1) { a0 = bat[tid]; a1 = bat[tid + 256]; }
  for (int k = 0; k < H; ++k) {
    float hv = hs[k];
    a0 += hv * W[(size_t)k * H + tid];
    a1 += hv * W[(size_t)k * H + tid + 256];
  }
  out[b * H + tid] = a0;
  out[b * H + tid + 256] = a1;
}

// ---- 3) fused score GEMM: score[b][t] = sum_j tanh((A@W)[m][j]+uvw[b][j])*V[j]
// A [M][H] fp32, Bt [H][H] bf16 pre-transposed [n][k]. 128x128 tiles, BK=32.
// grid (M/128, 4) block 256. score must be pre-zeroed (atomicAdd partials).
template <int LOGT>
__global__ __launch_bounds__(256)
void k_score(const float* __restrict__ A, const unsigned short* __restrict__ Bt,
             const float* __restrict__ uvw, const float* __restrict__ V,
             float* __restrict__ score) {
  constexpr int T = 1 << LOGT;
  __shared__ unsigned short As[128 * 32];  // [m][k] bf16, row = 64B
  __shared__ unsigned short Bs[128 * 32];  // [n][k] bf16
  const int tid = threadIdx.x;
  const int m0 = blockIdx.x * 128;
  const int n0 = blockIdx.y * 128;
  const int wv = tid >> 6, ln = tid & 63;
  const int quad = ln >> 4, l16 = ln & 15;
  const int wm = (wv >> 1) * 64, wn = (wv & 1) * 64;

  f4v acc[4][4] = {};

  const int ms = tid >> 1;          // staging row (0..127)
  const int ks = (tid & 1) * 16;    // staging col (0 or 16)

  for (int k0 = 0; k0 < H; k0 += 32) {
    __syncthreads();
    { // stage A: fp32 -> bf16 pack
      const float4* g = (const float4*)(A + (size_t)(m0 + ms) * H + k0 + ks);
      float4 f0 = g[0], f1 = g[1], f2 = g[2], f3 = g[3];
      uint4 p0, p1;
      p0.x = pk2bf(f0.x, f0.y); p0.y = pk2bf(f0.z, f0.w);
      p0.z = pk2bf(f1.x, f1.y); p0.w = pk2bf(f1.z, f1.w);
      p1.x = pk2bf(f2.x, f2.y); p1.y = pk2bf(f2.z, f2.w);
      p1.z = pk2bf(f3.x, f3.y); p1.w = pk2bf(f3.z, f3.w);
      uint4* d = (uint4*)&As[ms * 32 + ks];
      d[0] = p0; d[1] = p1;
    }
    { // stage B: already bf16
      const uint4* g = (const uint4*)(Bt + (size_t)(n0 + ms) * H + k0 + ks);
      uint4 v0 = g[0], v1 = g[1];
      uint4* d = (uint4*)&Bs[ms * 32 + ks];
      d[0] = v0; d[1] = v1;
    }
    __syncthreads();
    s8v afr[4], bfr[4];
#pragma unroll
    for (int mi = 0; mi < 4; ++mi)
      afr[mi] = *(const s8v*)&As[(wm + mi * 16 + l16) * 32 + quad * 8];
#pragma unroll
    for (int ni = 0; ni < 4; ++ni)
      bfr[ni] = *(const s8v*)&Bs[(wn + ni * 16 + l16) * 32 + quad * 8];
#pragma unroll
    for (int mi = 0; mi < 4; ++mi)
#pragma unroll
      for (int ni = 0; ni < 4; ++ni)
        acc[mi][ni] = __builtin_amdgcn_mfma_f32_16x16x32_bf16(afr[mi], bfr[ni], acc[mi][ni], 0, 0, 0);
  }

  // epilogue: tanh(+u) * V, reduce 128 cols of this block, atomic into score
  int jj[4]; float vv[4];
#pragma unroll
  for (int ni = 0; ni < 4; ++ni) {
    jj[ni] = n0 + wn + ni * 16 + l16;
    vv[ni] = V[jj[ni]];
  }
#pragma unroll
  for (int mi = 0; mi < 4; ++mi) {
    const int mrow0 = m0 + wm + mi * 16;          // 16-aligned -> single b per frag
    const int bidx = mrow0 >> LOGT;
    const float* up = uvw + (size_t)bidx * H;
    float uu[4];
#pragma unroll
    for (int ni = 0; ni < 4; ++ni) uu[ni] = up[jj[ni]];
#pragma unroll
    for (int r = 0; r < 4; ++r) {
      float sum = 0.f;
#pragma unroll
      for (int ni = 0; ni < 4; ++ni)
        sum += fast_tanh(acc[mi][ni][r] + uu[ni]) * vv[ni];
      // reduce across the 16 lanes of this quad (C/D: col = l16)
      sum += __shfl_xor(sum, 1);
      sum += __shfl_xor(sum, 2);
      sum += __shfl_xor(sum, 4);
      sum += __shfl_xor(sum, 8);
      if (l16 == 0) {
        const int mrow = mrow0 + quad * 4 + r;
        atomicAdd(&score[(size_t)bidx * T + (mrow & (T - 1))], sum);
      }
    }
  }
}

// ---- 4) softmax over t + weighted sum over frames/text -------------------
// grid 128: i<64 frames (T=512), else text (T=64). block 256.
__global__ void k_attn(const float* __restrict__ F, const float* __restrict__ Txt,
                       const float* __restrict__ score_v, const float* __restrict__ score_t,
                       float* __restrict__ hv_sum, float* __restrict__ ht_sum) {
  __shared__ float aw[TV];
  __shared__ float red[4];
  const int i = blockIdx.x, tid = threadIdx.x;
  const bool fr = i < BB;
  const int b = fr ? i : i - BB;
  const int T = fr ? TV : TT;
  const float* sc = fr ? (score_v + b * TV) : (score_t + b * TT);
  const float* X  = fr ? (F + (size_t)b * TV * H) : (Txt + (size_t)b * TT * H);
  float* out = fr ? hv_sum : ht_sum;

  float mx = -1e30f;
  for (int t = tid; t < T; t += 256) mx = fmaxf(mx, sc[t]);
  for (int d = 32; d; d >>= 1) mx = fmaxf(mx, __shfl_xor(mx, d));
  if ((tid & 63) == 0) red[tid >> 6] = mx;
  __syncthreads();
  mx = fmaxf(fmaxf(red[0], red[1]), fmaxf(red[2], red[3]));
  __syncthreads();

  float se = 0.f;
  for (int t = tid; t < T; t += 256) {
    float e = __expf(sc[t] - mx);
    aw[t] = e;
    se += e;
  }
  for (int d = 32; d; d >>= 1) se += __shfl_xor(se, d);
  if ((tid & 63) == 0) red[tid >> 6] = se;
  __syncthreads();                       // also orders aw[] writes
  se = red[0] + red[1] + red[2] + red[3];
  const float inv = 1.0f / se;

  float a0 = 0.f, a1 = 0.f;
  for (int t = 0; t < T; ++t) {
    float w = aw[t];
    a0 += w * X[(size_t)t * H + tid];
    a1 += w * X[(size_t)t * H + tid + 256];
  }
  out[b * H + tid] = a0 * inv;
  out[b * H + tid + 256] = a1 * inv;
}

// ---- 5) encoders + gate scores ------------------------------------------
// grid 128: i<64 -> v-stream (hv2, mv1, s[i]); i>=64 -> t-stream. block 256.
__global__ void k_final1(const float* __restrict__ hv_sum, const float* __restrict__ ht_sum,
                         const float* __restrict__ Wve, const float* __restrict__ bve,
                         const float* __restrict__ Wqe, const float* __restrict__ bqe,
                         const float* __restrict__ Vbv, const float* __restrict__ bbv,
                         const float* __restrict__ Vbt, const float* __restrict__ bbt,
                         const float* __restrict__ wbs, const float* __restrict__ wb,
                         float* __restrict__ hv2, float* __restrict__ ht2,
                         float* __restrict__ sArr) {
  __shared__ float vs[H];
  __shared__ float red[4];
  const int i = blockIdx.x, tid = threadIdx.x;
  const bool fr = i < BB;
  const int b = fr ? i : i - BB;
  const float* vin = (fr ? hv_sum : ht_sum) + (size_t)b * H;
  vs[tid] = vin[tid];
  vs[tid + 256] = vin[tid + 256];
  __syncthreads();

  // encoder: o1[j] = b1[j] + sum_k vs[k]*W1[j][k]  (W.T matmul: row-dot)
  const float* W1 = fr ? Wve : Wqe;
  const float* b1 = fr ? bve : bqe;
  float* o1 = (fr ? hv2 : ht2) + (size_t)b * H;
#pragma unroll
  for (int jj = 0; jj < 2; ++jj) {
    int j = tid + jj * 256;
    const float4* wr = (const float4*)(W1 + (size_t)j * H);
    const float4* vr = (const float4*)vs;
    float acc = 0.f;
    for (int k4 = 0; k4 < H / 4; ++k4) {
      float4 w4 = wr[k4], v4 = vr[k4];
      acc += w4.x * v4.x + w4.y * v4.y + w4.z * v4.z + w4.w * v4.w;
    }
    o1[j] = acc + b1[j];
  }

  // gate: m1[j] = wbs[b][j] + b2[j] + sum_k vs[k]*W2[k][j]; s_i = sum_j tanh(m1)*wb
  const float* W2 = fr ? Vbv : Vbt;
  const float* b2 = fr ? bbv : bbt;
  const int j0 = tid * 2;
  float g0 = 0.f, g1 = 0.f;
  for (int k = 0; k < H; ++k) {
    float v = vs[k];
    float2 w2 = *(const float2*)(W2 + (size_t)k * H + j0);
    g0 += v * w2.x;
    g1 += v * w2.y;
  }
  g0 += wbs[(size_t)b * H + j0] + b2[j0];
  g1 += wbs[(size_t)b * H + j0 + 1] + b2[j0 + 1];
  float sp = fast_tanh(g0) * wb[j0] + fast_tanh(g1) * wb[j0 + 1];
  for (int d = 32; d; d >>= 1) sp += __shfl_xor(sp, d);
  if ((tid & 63) == 0) red[tid >> 6] = sp;
  __syncthreads();
  if (tid == 0) sArr[i] = red[0] + red[1] + red[2] + red[3];
}

// ---- 6) beta softmax + output -------------------------------------------
// grid 64 (per b), block 256
__global__ void k_final2(const float* __restrict__ sArr, const float* __restrict__ hwhh,
                         const float* __restrict__ bh,
                         const float* __restrict__ hv2, const float* __restrict__ ht2,
                         float* __restrict__ out) {
  __shared__ float red[4];
  const int b = blockIdx.x, tid = threadIdx.x;
  float v = (tid < 2 * BB) ? sArr[tid] : -1e30f;
  float mx = v;
  for (int d = 32; d; d >>= 1) mx = fmaxf(mx, __shfl_xor(mx, d));
  if ((tid & 63) == 0) red[tid >> 6] = mx;
  __syncthreads();
  mx = fmaxf(fmaxf(red[0], red[1]), fmaxf(red[2], red[3]));
  __syncthreads();
  float e = (tid < 2 * BB) ? __expf(v - mx) : 0.f;
  for (int d = 32; d; d >>= 1) e += __shfl_xor(e, d);
  if ((tid & 63) == 0) red[tid >> 6] = e;
  __syncthreads();
  const float Z = red[0] + red[1] + red[2] + red[3];
  const float beta0 = __expf(sArr[0] - mx) / Z;
  const float beta1 = __expf(sArr[1] - mx) / Z;
#pragma unroll
  for (int jj = 0; jj < 2; ++jj) {
    int j = tid + jj * 256;
    float x = hwhh[(size_t)b * H + j] + bh[j] + beta0 * hv2[(size_t)b * H + j]
            + beta1 * ht2[(size_t)b * H + j];
    out[(size_t)b * H + j] = fast_tanh(x);
  }
}

// ---- launch --------------------------------------------------------------

extern "C" void kernel_launch(void* const* d_in, const int* in_sizes, int n_in,
                              void* d_out, int out_size, void* d_ws, size_t ws_size,
                              hipStream_t stream) {
  const float* h    = (const float*)d_in[0];
  const float* F    = (const float*)d_in[1];
  const float* Txt  = (const float*)d_in[2];
  const float* Wav  = (const float*)d_in[3];
  const float* Wat  = (const float*)d_in[4];
  const float* Uav  = (const float*)d_in[5];
  const float* Uat  = (const float*)d_in[6];
  const float* Vav  = (const float*)d_in[7];
  const float* Vat  = (const float*)d_in[8];
  const float* bav  = (const float*)d_in[9];
  const float* bat  = (const float*)d_in[10];
  const float* Whh  = (const float*)d_in[11];
  const float* bh   = (const float*)d_in[12];
  const float* Wve  = (const float*)d_in[13];
  const float* bve  = (const float*)d_in[14];
  const float* Wqe  = (const float*)d_in[15];
  const float* bqe  = (const float*)d_in[16];
  const float* Wb   = (const float*)d_in[17];
  const float* Vbv  = (const float*)d_in[18];
  const float* Vbt  = (const float*)d_in[19];
  const float* bbv  = (const float*)d_in[20];
  const float* bbt  = (const float*)d_in[21];
  const float* wb   = (const float*)d_in[22];
  float* out = (float*)d_out;

  char* ws = (char*)d_ws;
  size_t off = 0;
  auto alloc = [&](size_t bytes) -> void* {
    void* p = ws + off;
    off += (bytes + 255) & ~(size_t)255;
    return p;
  };
  unsigned short* Wavt = (unsigned short*)alloc((size_t)H * H * 2);
  unsigned short* Watt = (unsigned short*)alloc((size_t)H * H * 2);
  float* uv      = (float*)alloc((size_t)BB * H * 4);
  float* ut      = (float*)alloc((size_t)BB * H * 4);
  float* wbs     = (float*)alloc((size_t)BB * H * 4);
  float* hwhh    = (float*)alloc((size_t)BB * H * 4);
  float* score_v = (float*)alloc((size_t)BB * TV * 4);  // 131072 B (mult of 256)
  float* score_t = (float*)alloc((size_t)BB * TT * 4);  // contiguous after score_v
  float* hv_sum  = (float*)alloc((size_t)BB * H * 4);
  float* ht_sum  = (float*)alloc((size_t)BB * H * 4);
  float* hv2     = (float*)alloc((size_t)BB * H * 4);
  float* ht2     = (float*)alloc((size_t)BB * H * 4);
  float* sArr    = (float*)alloc((size_t)2 * BB * 4);
  // total ~2.3 MB of ws

  // zero the atomic score accumulators (ws is re-poisoned before every launch)
  hipMemsetAsync(score_v, 0, (size_t)(BB * TV + BB * TT) * 4, stream);

  k_prep_w<<<dim3(8, 8, 2), 256, 0, stream>>>(Wav, Wat, Wavt, Watt);
  k_hmm<<<dim3(64, 4), 256, 0, stream>>>(h, Uav, Uat, Wb, Whh, bav, bat, uv, ut, wbs, hwhh);
  k_score<9><<<dim3(BB * TV / 128, 4), 256, 0, stream>>>(F, Wavt, uv, Vav, score_v);
  k_score<6><<<dim3(BB * TT / 128, 4), 256, 0, stream>>>(Txt, Watt, ut, Vat, score_t);
  k_attn<<<128, 256, 0, stream>>>(F, Txt, score_v, score_t, hv_sum, ht_sum);
  k_final1<<<128, 256, 0, stream>>>(hv_sum, ht_sum, Wve, bve, Wqe, bqe,
                                    Vbv, bbv, Vbt, bbt, wbs, wb, hv2, ht2, sArr);
  k_final2<<<64, 256, 0, stream>>>(sArr, hwhh, bh, hv2, ht2, out);
}

// Round 2
// 298.739 us; speedup vs baseline: 1.0579x; 1.0579x over previous
//
#include <hip/hip_runtime.h>
#include <stdint.h>
#include <stddef.h>

#define H  512
#define BB 64
#define TV 512
#define TT 64

typedef short s8v __attribute__((ext_vector_type(8)));   // 8 bf16 (4 VGPRs)
typedef float f4v __attribute__((ext_vector_type(4)));   // MFMA accumulator

// ---- helpers -------------------------------------------------------------

__device__ inline unsigned short f2bf(float f) {
  unsigned int u = __float_as_uint(f);
  u = (u + 0x7fffu + ((u >> 16) & 1u)) >> 16;   // RNE
  return (unsigned short)u;
}

__device__ inline unsigned int pk2bf(float lo, float hi) {
  unsigned int a = __float_as_uint(lo);
  a = (a + 0x7fffu + ((a >> 16) & 1u)) >> 16;
  unsigned int b = __float_as_uint(hi);
  b = (b + 0x7fffu + ((b >> 16) & 1u)) & 0xffff0000u;
  return a | b;
}

__device__ inline float fast_tanh(float x) {
  x = fminf(15.f, fmaxf(-15.f, x));
  float e = __expf(2.f * x);
  return (e - 1.f) * __builtin_amdgcn_rcpf(e + 1.f);
}

// async global->LDS, 16 bytes per lane (global_load_lds_dwordx4)
__device__ inline void gld16(const unsigned short* g, unsigned short* l) {
  __builtin_amdgcn_global_load_lds(
      (const __attribute__((address_space(1))) unsigned int*)g,
      (__attribute__((address_space(3))) unsigned int*)l, 16, 0, 0);
}

// ---- 0) convert F / Txt -> bf16 (grid-stride-free, exact cover) ----------
// 8 elems/thread; grid = ceil((NF+NT)/8/256)
__global__ void k_conv(const float* __restrict__ F, const float* __restrict__ Txt,
                       unsigned short* __restrict__ Fb, unsigned short* __restrict__ Tb) {
  const size_t NF = (size_t)BB * TV * H;
  const size_t NT = (size_t)BB * TT * H;
  size_t i = ((size_t)blockIdx.x * 256 + threadIdx.x) * 8;
  const float* src; unsigned short* dst;
  if (i < NF) { src = F + i; dst = Fb + i; }
  else {
    size_t j = i - NF;
    if (j >= NT) return;
    src = Txt + j; dst = Tb + j;
  }
  float4 f0 = *(const float4*)src;
  float4 f1 = *(const float4*)(src + 4);
  uint4 p;
  p.x = pk2bf(f0.x, f0.y); p.y = pk2bf(f0.z, f0.w);
  p.z = pk2bf(f1.x, f1.y); p.w = pk2bf(f1.z, f1.w);
  *(uint4*)dst = p;
}

// ---- 1) transpose + convert Wav/Wat -> bf16 [n][k] -----------------------
__global__ void k_prep_w(const float* __restrict__ Wav, const float* __restrict__ Wat,
                         unsigned short* __restrict__ Wavt, unsigned short* __restrict__ Watt) {
  __shared__ float tile[64][65];
  const float* src = blockIdx.z ? Wat : Wav;
  unsigned short* dst = blockIdx.z ? Watt : Wavt;
  const int k0 = blockIdx.x * 64, j0 = blockIdx.y * 64;
  const int tid = threadIdx.x;
  for (int i = 0; i < 16; ++i) {
    int e = tid + i * 256; int r = e >> 6, c = e & 63;
    tile[r][c] = src[(size_t)(k0 + r) * H + j0 + c];
  }
  __syncthreads();
  for (int i = 0; i < 16; ++i) {
    int e = tid + i * 256; int r = e >> 6, c = e & 63;
    dst[(size_t)(j0 + r) * H + k0 + c] = f2bf(tile[c][r]);
  }
}

// ---- 2) the four h-driven matmuls ---------------------------------------
__global__ void k_hmm(const float* __restrict__ h,
                      const float* __restrict__ Uav, const float* __restrict__ Uat,
                      const float* __restrict__ Wb,  const float* __restrict__ Whh,
                      const float* __restrict__ bav, const float* __restrict__ bat,
                      float* __restrict__ uv, float* __restrict__ ut,
                      float* __restrict__ wbs, float* __restrict__ hwhh) {
  __shared__ float hs[H];
  const int b = blockIdx.x, w = blockIdx.y, tid = threadIdx.x;
  const float* W = (w == 0) ? Uav : (w == 1) ? Uat : (w == 2) ? Wb : Whh;
  float* out     = (w == 0) ? uv  : (w == 1) ? ut  : (w == 2) ? wbs : hwhh;
  hs[tid] = h[b * H + tid];
  hs[tid + 256] = h[b * H + tid + 256];
  __syncthreads();
  float a0 = 0.f, a1 = 0.f;
  if (w == 0) { a0 = bav[tid]; a1 = bav[tid + 256]; }
  else if (w == 1) { a0 = bat[tid]; a1 = bat[tid + 256]; }
  for (int k = 0; k < H; ++k) {
    float hv = hs[k];
    a0 += hv * W[(size_t)k * H + tid];
    a1 += hv * W[(size_t)k * H + tid + 256];
  }
  out[b * H + tid] = a0;
  out[b * H + tid + 256] = a1;
}

// ---- 3) fused score GEMM (bf16 A via global_load_lds, m97 pattern) -------
// score[b][t] = sum_j tanh((A@W)[m][j] + uvw[b][j]) * V[j]
// A [M][H] bf16, Bt [H][H] bf16 [n][k]. 128x128 tile, BK=32. score pre-zeroed.
template <int LOGT>
__global__ __launch_bounds__(256)
void k_score(const unsigned short* __restrict__ A, const unsigned short* __restrict__ Bt,
             const float* __restrict__ uvw, const float* __restrict__ V,
             float* __restrict__ score) {
  constexpr int T = 1 << LOGT;
  __shared__ unsigned short As[128 * 32];  // [m][k], rows of 64B
  __shared__ unsigned short Bs[128 * 32];  // [n][k]
  const int tid = threadIdx.x;
  const int m0 = blockIdx.x * 128;
  const int n0 = blockIdx.y * 128;
  const int wv = tid >> 6, ln = tid & 63;
  const int quad = ln >> 4, l16 = ln & 15;
  const int wm = (wv >> 1) * 64, wn = (wv & 1) * 64;

  // staging: 512 16B-slots per tile; slot s -> row s>>2, kcol (s&3)*8.
  // wave wv covers slots [wv*128, wv*128+64) and [+64, +128) -> lds byte = slot*16
  const int s0 = wv * 128 + ln;
  const int s1 = s0 + 64;
  const int r0 = s0 >> 2, c0 = (s0 & 3) * 8;
  const int r1 = s1 >> 2, c1 = (s1 & 3) * 8;

  const unsigned short* Ag0 = A + (size_t)(m0 + r0) * H + c0;
  const unsigned short* Ag1 = A + (size_t)(m0 + r1) * H + c1;
  const unsigned short* Bg0 = Bt + (size_t)(n0 + r0) * H + c0;
  const unsigned short* Bg1 = Bt + (size_t)(n0 + r1) * H + c1;
  unsigned short* Al0 = &As[s0 * 8];
  unsigned short* Al1 = &As[s1 * 8];
  unsigned short* Bl0 = &Bs[s0 * 8];
  unsigned short* Bl1 = &Bs[s1 * 8];

  f4v acc[4][4] = {};

  for (int k0 = 0; k0 < H; k0 += 32) {
    __syncthreads();
    gld16(Ag0 + k0, Al0);
    gld16(Ag1 + k0, Al1);
    gld16(Bg0 + k0, Bl0);
    gld16(Bg1 + k0, Bl1);
    __syncthreads();   // compiler drains vmcnt before s_barrier
    s8v afr[4], bfr[4];
#pragma unroll
    for (int mi = 0; mi < 4; ++mi)
      afr[mi] = *(const s8v*)&As[(wm + mi * 16 + l16) * 32 + quad * 8];
#pragma unroll
    for (int ni = 0; ni < 4; ++ni)
      bfr[ni] = *(const s8v*)&Bs[(wn + ni * 16 + l16) * 32 + quad * 8];
#pragma unroll
    for (int mi = 0; mi < 4; ++mi)
#pragma unroll
      for (int ni = 0; ni < 4; ++ni)
        acc[mi][ni] = __builtin_amdgcn_mfma_f32_16x16x32_bf16(afr[mi], bfr[ni], acc[mi][ni], 0, 0, 0);
  }

  // epilogue: tanh(+u) * V, quad-reduce, atomic into score
  int jj[4]; float vv[4];
#pragma unroll
  for (int ni = 0; ni < 4; ++ni) {
    jj[ni] = n0 + wn + ni * 16 + l16;
    vv[ni] = V[jj[ni]];
  }
#pragma unroll
  for (int mi = 0; mi < 4; ++mi) {
    const int mrow0 = m0 + wm + mi * 16;     // 16-aligned -> one b per frag
    const int bidx = mrow0 >> LOGT;
    const float* up = uvw + (size_t)bidx * H;
    float uu[4];
#pragma unroll
    for (int ni = 0; ni < 4; ++ni) uu[ni] = up[jj[ni]];
#pragma unroll
    for (int r = 0; r < 4; ++r) {
      float sum = 0.f;
#pragma unroll
      for (int ni = 0; ni < 4; ++ni)
        sum += fast_tanh(acc[mi][ni][r] + uu[ni]) * vv[ni];
      sum += __shfl_xor(sum, 1);
      sum += __shfl_xor(sum, 2);
      sum += __shfl_xor(sum, 4);
      sum += __shfl_xor(sum, 8);
      if (l16 == 0) {
        const int mrow = mrow0 + quad * 4 + r;
        atomicAdd(&score[(size_t)bidx * T + (mrow & (T - 1))], sum);
      }
    }
  }
}

// ---- 4a) softmax in place over score rows --------------------------------
// grid 128: i<64 frames row (T=512), else text row (T=64). block 256.
__global__ void k_softmax(float* __restrict__ score_v, float* __restrict__ score_t) {
  __shared__ float red[4];
  const int i = blockIdx.x, tid = threadIdx.x;
  const bool fr = i < BB;
  float* sc = fr ? (score_v + i * TV) : (score_t + (i - BB) * TT);
  const int T = fr ? TV : TT;
  float v0 = (tid < T) ? sc[tid] : -1e30f;
  float v1 = fr ? sc[tid + 256] : -1e30f;
  float mx = fmaxf(v0, v1);
  for (int d = 32; d; d >>= 1) mx = fmaxf(mx, __shfl_xor(mx, d));
  if ((tid & 63) == 0) red[tid >> 6] = mx;
  __syncthreads();
  mx = fmaxf(fmaxf(red[0], red[1]), fmaxf(red[2], red[3]));
  __syncthreads();
  float e0 = (tid < T) ? __expf(v0 - mx) : 0.f;
  float e1 = fr ? __expf(v1 - mx) : 0.f;
  float se = e0 + e1;
  for (int d = 32; d; d >>= 1) se += __shfl_xor(se, d);
  if ((tid & 63) == 0) red[tid >> 6] = se;
  __syncthreads();
  const float inv = 1.f / (red[0] + red[1] + red[2] + red[3]);
  if (tid < T) sc[tid] = e0 * inv;
  if (fr) sc[tid + 256] = e1 * inv;
}

// ---- 4b) weighted sum over bf16 frames/text, chunked + atomic ------------
// grid (64, 9): ch<8 -> frames t-chunk of 64; ch==8 -> text (64 t). block 256.
// hv_sum/ht_sum pre-zeroed.
__global__ void k_wsum(const unsigned short* __restrict__ Fb, const unsigned short* __restrict__ Tb,
                       const float* __restrict__ aw_v, const float* __restrict__ aw_t,
                       float* __restrict__ hv_sum, float* __restrict__ ht_sum) {
  __shared__ float w[64];
  const int b = blockIdx.x, ch = blockIdx.y, tid = threadIdx.x;
  const bool fr = ch < 8;
  const unsigned short* X = fr ? (Fb + ((size_t)b * TV + ch * 64) * H)
                               : (Tb + (size_t)b * TT * H);
  const float* ww = fr ? (aw_v + b * TV + ch * 64) : (aw_t + b * TT);
  float* out = fr ? (hv_sum + b * H) : (ht_sum + b * H);
  if (tid < 64) w[tid] = ww[tid];
  __syncthreads();
  const int j = tid * 2;
  float a0 = 0.f, a1 = 0.f;
  for (int t = 0; t < 64; ++t) {
    unsigned u = *(const unsigned*)(X + (size_t)t * H + j);
    float wt = w[t];
    a0 += wt * __uint_as_float(u << 16);
    a1 += wt * __uint_as_float(u & 0xffff0000u);
  }
  atomicAdd(&out[j], a0);
  atomicAdd(&out[j + 1], a1);
}

// ---- 5) encoders + gate scores ------------------------------------------
__global__ void k_final1(const float* __restrict__ hv_sum, const float* __restrict__ ht_sum,
                         const float* __restrict__ Wve, const float* __restrict__ bve,
                         const float* __restrict__ Wqe, const float* __restrict__ bqe,
                         const float* __restrict__ Vbv, const float* __restrict__ bbv,
                         const float* __restrict__ Vbt, const float* __restrict__ bbt,
                         const float* __restrict__ wbs, const float* __restrict__ wb,
                         float* __restrict__ hv2, float* __restrict__ ht2,
                         float* __restrict__ sArr) {
  __shared__ float vs[H];
  __shared__ float red[4];
  const int i = blockIdx.x, tid = threadIdx.x;
  const bool fr = i < BB;
  const int b = fr ? i : i - BB;
  const float* vin = (fr ? hv_sum : ht_sum) + (size_t)b * H;
  vs[tid] = vin[tid];
  vs[tid + 256] = vin[tid + 256];
  __syncthreads();

  const float* W1 = fr ? Wve : Wqe;
  const float* b1 = fr ? bve : bqe;
  float* o1 = (fr ? hv2 : ht2) + (size_t)b * H;
#pragma unroll
  for (int jj = 0; jj < 2; ++jj) {
    int j = tid + jj * 256;
    const float4* wr = (const float4*)(W1 + (size_t)j * H);
    const float4* vr = (const float4*)vs;
    float acc = 0.f;
    for (int k4 = 0; k4 < H / 4; ++k4) {
      float4 w4 = wr[k4], v4 = vr[k4];
      acc += w4.x * v4.x + w4.y * v4.y + w4.z * v4.z + w4.w * v4.w;
    }
    o1[j] = acc + b1[j];
  }

  const float* W2 = fr ? Vbv : Vbt;
  const float* b2 = fr ? bbv : bbt;
  const int j0 = tid * 2;
  float g0 = 0.f, g1 = 0.f;
  for (int k = 0; k < H; ++k) {
    float v = vs[k];
    float2 w2 = *(const float2*)(W2 + (size_t)k * H + j0);
    g0 += v * w2.x;
    g1 += v * w2.y;
  }
  g0 += wbs[(size_t)b * H + j0] + b2[j0];
  g1 += wbs[(size_t)b * H + j0 + 1] + b2[j0 + 1];
  float sp = fast_tanh(g0) * wb[j0] + fast_tanh(g1) * wb[j0 + 1];
  for (int d = 32; d; d >>= 1) sp += __shfl_xor(sp, d);
  if ((tid & 63) == 0) red[tid >> 6] = sp;
  __syncthreads();
  if (tid == 0) sArr[i] = red[0] + red[1] + red[2] + red[3];
}

// ---- 6) beta softmax + output -------------------------------------------
__global__ void k_final2(const float* __restrict__ sArr, const float* __restrict__ hwhh,
                         const float* __restrict__ bh,
                         const float* __restrict__ hv2, const float* __restrict__ ht2,
                         float* __restrict__ out) {
  __shared__ float red[4];
  const int b = blockIdx.x, tid = threadIdx.x;
  float v = (tid < 2 * BB) ? sArr[tid] : -1e30f;
  float mx = v;
  for (int d = 32; d; d >>= 1) mx = fmaxf(mx, __shfl_xor(mx, d));
  if ((tid & 63) == 0) red[tid >> 6] = mx;
  __syncthreads();
  mx = fmaxf(fmaxf(red[0], red[1]), fmaxf(red[2], red[3]));
  __syncthreads();
  float e = (tid < 2 * BB) ? __expf(v - mx) : 0.f;
  for (int d = 32; d; d >>= 1) e += __shfl_xor(e, d);
  if ((tid & 63) == 0) red[tid >> 6] = e;
  __syncthreads();
  const float Z = red[0] + red[1] + red[2] + red[3];
  const float beta0 = __expf(sArr[0] - mx) / Z;
  const float beta1 = __expf(sArr[1] - mx) / Z;
#pragma unroll
  for (int jj = 0; jj < 2; ++jj) {
    int j = tid + jj * 256;
    float x = hwhh[(size_t)b * H + j] + bh[j] + beta0 * hv2[(size_t)b * H + j]
            + beta1 * ht2[(size_t)b * H + j];
    out[(size_t)b * H + j] = fast_tanh(x);
  }
}

// ---- launch --------------------------------------------------------------

extern "C" void kernel_launch(void* const* d_in, const int* in_sizes, int n_in,
                              void* d_out, int out_size, void* d_ws, size_t ws_size,
                              hipStream_t stream) {
  const float* h    = (const float*)d_in[0];
  const float* F    = (const float*)d_in[1];
  const float* Txt  = (const float*)d_in[2];
  const float* Wav  = (const float*)d_in[3];
  const float* Wat  = (const float*)d_in[4];
  const float* Uav  = (const float*)d_in[5];
  const float* Uat  = (const float*)d_in[6];
  const float* Vav  = (const float*)d_in[7];
  const float* Vat  = (const float*)d_in[8];
  const float* bav  = (const float*)d_in[9];
  const float* bat  = (const float*)d_in[10];
  const float* Whh  = (const float*)d_in[11];
  const float* bh   = (const float*)d_in[12];
  const float* Wve  = (const float*)d_in[13];
  const float* bve  = (const float*)d_in[14];
  const float* Wqe  = (const float*)d_in[15];
  const float* bqe  = (const float*)d_in[16];
  const float* Wb   = (const float*)d_in[17];
  const float* Vbv  = (const float*)d_in[18];
  const float* Vbt  = (const float*)d_in[19];
  const float* bbv  = (const float*)d_in[20];
  const float* bbt  = (const float*)d_in[21];
  const float* wb   = (const float*)d_in[22];
  float* out = (float*)d_out;

  char* ws = (char*)d_ws;
  size_t off = 0;
  auto alloc = [&](size_t bytes) -> void* {
    void* p = ws + off;
    off += (bytes + 255) & ~(size_t)255;
    return p;
  };
  // zero-init region must stay contiguous: score_v, score_t, hv_sum, ht_sum
  float* score_v = (float*)alloc((size_t)BB * TV * 4);   // 131072 B
  float* score_t = (float*)alloc((size_t)BB * TT * 4);   //  16384 B
  float* hv_sum  = (float*)alloc((size_t)BB * H * 4);    // 131072 B
  float* ht_sum  = (float*)alloc((size_t)BB * H * 4);    // 131072 B
  unsigned short* Wavt = (unsigned short*)alloc((size_t)H * H * 2);
  unsigned short* Watt = (unsigned short*)alloc((size_t)H * H * 2);
  unsigned short* Fb   = (unsigned short*)alloc((size_t)BB * TV * H * 2);  // 33.5 MB
  unsigned short* Tb   = (unsigned short*)alloc((size_t)BB * TT * H * 2);  // 4.2 MB
  float* uv      = (float*)alloc((size_t)BB * H * 4);
  float* ut      = (float*)alloc((size_t)BB * H * 4);
  float* wbs     = (float*)alloc((size_t)BB * H * 4);
  float* hwhh    = (float*)alloc((size_t)BB * H * 4);
  float* hv2     = (float*)alloc((size_t)BB * H * 4);
  float* ht2     = (float*)alloc((size_t)BB * H * 4);
  float* sArr    = (float*)alloc((size_t)2 * BB * 4);

  hipMemsetAsync(score_v, 0, (size_t)(BB * TV + BB * TT + 2 * BB * H) * 4, stream);

  const size_t NTOT = (size_t)BB * (TV + TT) * H;
  k_conv<<<dim3((NTOT / 8 + 255) / 256), 256, 0, stream>>>(F, Txt, Fb, Tb);
  k_prep_w<<<dim3(8, 8, 2), 256, 0, stream>>>(Wav, Wat, Wavt, Watt);
  k_hmm<<<dim3(64, 4), 256, 0, stream>>>(h, Uav, Uat, Wb, Whh, bav, bat, uv, ut, wbs, hwhh);
  k_score<9><<<dim3(BB * TV / 128, 4), 256, 0, stream>>>(Fb, Wavt, uv, Vav, score_v);
  k_score<6><<<dim3(BB * TT / 128, 4), 256, 0, stream>>>(Tb, Watt, ut, Vat, score_t);
  k_softmax<<<128, 256, 0, stream>>>(score_v, score_t);
  k_wsum<<<dim3(64, 9), 256, 0, stream>>>(Fb, Tb, score_v, score_t, hv_sum, ht_sum);
  k_final1<<<128, 256, 0, stream>>>(hv_sum, ht_sum, Wve, bve, Wqe, bqe,
                                    Vbv, bbv, Vbt, bbt, wbs, wb, hv2, ht2, sArr);
  k_final2<<<64, 256, 0, stream>>>(sArr, hwhh, bh, hv2, ht2, out);
}

// Round 3
// 234.826 us; speedup vs baseline: 1.3458x; 1.2722x over previous
//
#include <hip/hip_runtime.h>
#include <stdint.h>
#include <stddef.h>

#define H  512
#define BB 64
#define TV 512
#define TT 64

typedef short s8v __attribute__((ext_vector_type(8)));   // 8 bf16 (4 VGPRs)
typedef float f4v __attribute__((ext_vector_type(4)));   // MFMA accumulator

// ---- helpers -------------------------------------------------------------

__device__ inline unsigned short f2bf(float f) {
  unsigned int u = __float_as_uint(f);
  u = (u + 0x7fffu + ((u >> 16) & 1u)) >> 16;   // RNE
  return (unsigned short)u;
}

__device__ inline unsigned int pk2bf(float lo, float hi) {
  unsigned int a = __float_as_uint(lo);
  a = (a + 0x7fffu + ((a >> 16) & 1u)) >> 16;
  unsigned int b = __float_as_uint(hi);
  b = (b + 0x7fffu + ((b >> 16) & 1u)) & 0xffff0000u;
  return a | b;
}

__device__ inline float fast_tanh(float x) {
  x = fminf(15.f, fmaxf(-15.f, x));
  float e = __expf(2.f * x);
  return (e - 1.f) * __builtin_amdgcn_rcpf(e + 1.f);
}

// async global->LDS, 16 bytes per lane (global_load_lds_dwordx4)
__device__ inline void gld16(const unsigned short* g, unsigned short* l) {
  __builtin_amdgcn_global_load_lds(
      (const __attribute__((address_space(1))) unsigned int*)g,
      (__attribute__((address_space(3))) unsigned int*)l, 16, 0, 0);
}

// ---- 0) convert F / Txt / h -> bf16 --------------------------------------
// 8 elems/thread; grid covers NF+NT+NH exactly
__global__ void k_conv(const float* __restrict__ F, const float* __restrict__ Txt,
                       const float* __restrict__ h,
                       unsigned short* __restrict__ Fb, unsigned short* __restrict__ Tb,
                       unsigned short* __restrict__ hb) {
  const size_t NF = (size_t)BB * TV * H;
  const size_t NT = (size_t)BB * TT * H;
  const size_t NH = (size_t)BB * H;
  size_t i = ((size_t)blockIdx.x * 256 + threadIdx.x) * 8;
  const float* src; unsigned short* dst;
  if (i < NF) { src = F + i; dst = Fb + i; }
  else if (i < NF + NT) { size_t j = i - NF; src = Txt + j; dst = Tb + j; }
  else { size_t j = i - NF - NT; if (j >= NH) return; src = h + j; dst = hb + j; }
  float4 f0 = *(const float4*)src;
  float4 f1 = *(const float4*)(src + 4);
  uint4 p;
  p.x = pk2bf(f0.x, f0.y); p.y = pk2bf(f0.z, f0.w);
  p.z = pk2bf(f1.x, f1.y); p.w = pk2bf(f1.z, f1.w);
  *(uint4*)dst = p;
}

// ---- 0b) convert hv_sum||ht_sum (contiguous) -> bf16 ---------------------
__global__ void k_conv2(const float* __restrict__ src, unsigned short* __restrict__ dst) {
  size_t i = ((size_t)blockIdx.x * 256 + threadIdx.x) * 8;   // grid covers 2*BB*H exactly
  float4 f0 = *(const float4*)(src + i);
  float4 f1 = *(const float4*)(src + i + 4);
  uint4 p;
  p.x = pk2bf(f0.x, f0.y); p.y = pk2bf(f0.z, f0.w);
  p.z = pk2bf(f1.x, f1.y); p.w = pk2bf(f1.z, f1.w);
  *(uint4*)(dst + i) = p;
}

// ---- 1) prep 10 weight matrices -> bf16 into Wbf[z] ----------------------
// z: 0 Wav^T, 1 Wat^T, 2 Uav^T, 3 Uat^T, 4 Wb^T, 5 Whh^T, 6 Wve copy,
//    7 Wqe copy, 8 Vbv^T, 9 Vbt^T.  grid (8,8,10) block 256.
__global__ void k_prep_w(const float* __restrict__ Wav, const float* __restrict__ Wat,
                         const float* __restrict__ Uav, const float* __restrict__ Uat,
                         const float* __restrict__ Wb,  const float* __restrict__ Whh,
                         const float* __restrict__ Wve, const float* __restrict__ Wqe,
                         const float* __restrict__ Vbv, const float* __restrict__ Vbt,
                         unsigned short* __restrict__ Wbf) {
  __shared__ float tile[64][65];
  const int z = blockIdx.z;
  const float* src =
      (z == 0) ? Wav : (z == 1) ? Wat : (z == 2) ? Uav : (z == 3) ? Uat :
      (z == 4) ? Wb  : (z == 5) ? Whh : (z == 6) ? Wve : (z == 7) ? Wqe :
      (z == 8) ? Vbv : Vbt;
  unsigned short* dst = Wbf + (size_t)z * H * H;
  const int k0 = blockIdx.x * 64, j0 = blockIdx.y * 64;
  const int tid = threadIdx.x;
  if (z == 6 || z == 7) {          // straight convert
    for (int i = 0; i < 16; ++i) {
      int e = tid + i * 256; int r = e >> 6, c = e & 63;
      dst[(size_t)(k0 + r) * H + j0 + c] = f2bf(src[(size_t)(k0 + r) * H + j0 + c]);
    }
    return;
  }
  for (int i = 0; i < 16; ++i) {
    int e = tid + i * 256; int r = e >> 6, c = e & 63;
    tile[r][c] = src[(size_t)(k0 + r) * H + j0 + c];
  }
  __syncthreads();
  for (int i = 0; i < 16; ++i) {
    int e = tid + i * 256; int r = e >> 6, c = e & 63;
    dst[(size_t)(j0 + r) * H + k0 + c] = f2bf(tile[c][r]);
  }
}

// ---- 2) batched MFMA GEMM: C[seg][64][512] = A_seg @ Bt[seg]^T -----------
// A_seg: aMode==0 -> A0 always; aMode==1 -> (seg&1)?A1:A0.  Bt: 4 contiguous
// [512][512] bf16 pre-transposed mats. bias0/bias1 added for seg 0/1 if set.
// grid (8 n-tiles, 4 segs), block 256.
__global__ __launch_bounds__(256)
void k_gemm64(const unsigned short* __restrict__ A0, const unsigned short* __restrict__ A1,
              const unsigned short* __restrict__ Bt, float* __restrict__ C,
              const float* __restrict__ bias0, const float* __restrict__ bias1,
              int aMode) {
  __shared__ unsigned short As[64 * 32];
  __shared__ unsigned short Bs[64 * 32];
  const int tid = threadIdx.x;
  const int n0 = blockIdx.x * 64;
  const int seg = blockIdx.y;
  const unsigned short* A = (aMode && (seg & 1)) ? A1 : A0;
  const unsigned short* B = Bt + (size_t)seg * H * H;

  // staging: 256 slots of 16B per tile; slot t: row t>>2, kcol (t&3)*8
  const int r = tid >> 2, c = (tid & 3) * 8;
  const unsigned short* Ag = A + (size_t)r * H + c;
  const unsigned short* Bg = B + (size_t)(n0 + r) * H + c;
  unsigned short* Al = &As[tid * 8];
  unsigned short* Bl = &Bs[tid * 8];

  const int wv = tid >> 6, ln = tid & 63;
  const int quad = ln >> 4, l16 = ln & 15;
  const int wm = (wv >> 1) * 32, wn = (wv & 1) * 32;

  f4v acc[2][2] = {};
  for (int k0 = 0; k0 < H; k0 += 32) {
    __syncthreads();
    gld16(Ag + k0, Al);
    gld16(Bg + k0, Bl);
    __syncthreads();
    s8v afr[2], bfr[2];
#pragma unroll
    for (int mi = 0; mi < 2; ++mi)
      afr[mi] = *(const s8v*)&As[(wm + mi * 16 + l16) * 32 + quad * 8];
#pragma unroll
    for (int ni = 0; ni < 2; ++ni)
      bfr[ni] = *(const s8v*)&Bs[(wn + ni * 16 + l16) * 32 + quad * 8];
#pragma unroll
    for (int mi = 0; mi < 2; ++mi)
#pragma unroll
      for (int ni = 0; ni < 2; ++ni)
        acc[mi][ni] = __builtin_amdgcn_mfma_f32_16x16x32_bf16(afr[mi], bfr[ni], acc[mi][ni], 0, 0, 0);
  }

  const float* bias = (seg == 0) ? bias0 : (seg == 1) ? bias1 : nullptr;
  float* Cs = C + (size_t)seg * BB * H;
#pragma unroll
  for (int mi = 0; mi < 2; ++mi)
#pragma unroll
    for (int ni = 0; ni < 2; ++ni)
#pragma unroll
      for (int rr = 0; rr < 4; ++rr) {
        const int row = wm + mi * 16 + quad * 4 + rr;   // b
        const int j = n0 + wn + ni * 16 + l16;          // col
        float v = acc[mi][ni][rr];
        if (bias) v += bias[j];
        Cs[(size_t)row * H + j] = v;
      }
}

// ---- 3) fused score GEMM (unchanged from R2) -----------------------------
template <int LOGT>
__global__ __launch_bounds__(256)
void k_score(const unsigned short* __restrict__ A, const unsigned short* __restrict__ Bt,
             const float* __restrict__ uvw, const float* __restrict__ V,
             float* __restrict__ score) {
  constexpr int T = 1 << LOGT;
  __shared__ unsigned short As[128 * 32];
  __shared__ unsigned short Bs[128 * 32];
  const int tid = threadIdx.x;
  const int m0 = blockIdx.x * 128;
  const int n0 = blockIdx.y * 128;
  const int wv = tid >> 6, ln = tid & 63;
  const int quad = ln >> 4, l16 = ln & 15;
  const int wm = (wv >> 1) * 64, wn = (wv & 1) * 64;

  const int s0 = wv * 128 + ln;
  const int s1 = s0 + 64;
  const int r0 = s0 >> 2, c0 = (s0 & 3) * 8;
  const int r1 = s1 >> 2, c1 = (s1 & 3) * 8;

  const unsigned short* Ag0 = A + (size_t)(m0 + r0) * H + c0;
  const unsigned short* Ag1 = A + (size_t)(m0 + r1) * H + c1;
  const unsigned short* Bg0 = Bt + (size_t)(n0 + r0) * H + c0;
  const unsigned short* Bg1 = Bt + (size_t)(n0 + r1) * H + c1;
  unsigned short* Al0 = &As[s0 * 8];
  unsigned short* Al1 = &As[s1 * 8];
  unsigned short* Bl0 = &Bs[s0 * 8];
  unsigned short* Bl1 = &Bs[s1 * 8];

  f4v acc[4][4] = {};

  for (int k0 = 0; k0 < H; k0 += 32) {
    __syncthreads();
    gld16(Ag0 + k0, Al0);
    gld16(Ag1 + k0, Al1);
    gld16(Bg0 + k0, Bl0);
    gld16(Bg1 + k0, Bl1);
    __syncthreads();
    s8v afr[4], bfr[4];
#pragma unroll
    for (int mi = 0; mi < 4; ++mi)
      afr[mi] = *(const s8v*)&As[(wm + mi * 16 + l16) * 32 + quad * 8];
#pragma unroll
    for (int ni = 0; ni < 4; ++ni)
      bfr[ni] = *(const s8v*)&Bs[(wn + ni * 16 + l16) * 32 + quad * 8];
#pragma unroll
    for (int mi = 0; mi < 4; ++mi)
#pragma unroll
      for (int ni = 0; ni < 4; ++ni)
        acc[mi][ni] = __builtin_amdgcn_mfma_f32_16x16x32_bf16(afr[mi], bfr[ni], acc[mi][ni], 0, 0, 0);
  }

  int jj[4]; float vv[4];
#pragma unroll
  for (int ni = 0; ni < 4; ++ni) {
    jj[ni] = n0 + wn + ni * 16 + l16;
    vv[ni] = V[jj[ni]];
  }
#pragma unroll
  for (int mi = 0; mi < 4; ++mi) {
    const int mrow0 = m0 + wm + mi * 16;
    const int bidx = mrow0 >> LOGT;
    const float* up = uvw + (size_t)bidx * H;
    float uu[4];
#pragma unroll
    for (int ni = 0; ni < 4; ++ni) uu[ni] = up[jj[ni]];
#pragma unroll
    for (int r = 0; r < 4; ++r) {
      float sum = 0.f;
#pragma unroll
      for (int ni = 0; ni < 4; ++ni)
        sum += fast_tanh(acc[mi][ni][r] + uu[ni]) * vv[ni];
      sum += __shfl_xor(sum, 1);
      sum += __shfl_xor(sum, 2);
      sum += __shfl_xor(sum, 4);
      sum += __shfl_xor(sum, 8);
      if (l16 == 0) {
        const int mrow = mrow0 + quad * 4 + r;
        atomicAdd(&score[(size_t)bidx * T + (mrow & (T - 1))], sum);
      }
    }
  }
}

// ---- 4a) softmax in place over score rows --------------------------------
__global__ void k_softmax(float* __restrict__ score_v, float* __restrict__ score_t) {
  __shared__ float red[4];
  const int i = blockIdx.x, tid = threadIdx.x;
  const bool fr = i < BB;
  float* sc = fr ? (score_v + i * TV) : (score_t + (i - BB) * TT);
  const int T = fr ? TV : TT;
  float v0 = (tid < T) ? sc[tid] : -1e30f;
  float v1 = fr ? sc[tid + 256] : -1e30f;
  float mx = fmaxf(v0, v1);
  for (int d = 32; d; d >>= 1) mx = fmaxf(mx, __shfl_xor(mx, d));
  if ((tid & 63) == 0) red[tid >> 6] = mx;
  __syncthreads();
  mx = fmaxf(fmaxf(red[0], red[1]), fmaxf(red[2], red[3]));
  __syncthreads();
  float e0 = (tid < T) ? __expf(v0 - mx) : 0.f;
  float e1 = fr ? __expf(v1 - mx) : 0.f;
  float se = e0 + e1;
  for (int d = 32; d; d >>= 1) se += __shfl_xor(se, d);
  if ((tid & 63) == 0) red[tid >> 6] = se;
  __syncthreads();
  const float inv = 1.f / (red[0] + red[1] + red[2] + red[3]);
  if (tid < T) sc[tid] = e0 * inv;
  if (fr) sc[tid + 256] = e1 * inv;
}

// ---- 4b) weighted sum over bf16 frames/text, chunked + atomic ------------
__global__ void k_wsum(const unsigned short* __restrict__ Fb, const unsigned short* __restrict__ Tb,
                       const float* __restrict__ aw_v, const float* __restrict__ aw_t,
                       float* __restrict__ hv_sum, float* __restrict__ ht_sum) {
  __shared__ float w[64];
  const int b = blockIdx.x, ch = blockIdx.y, tid = threadIdx.x;
  const bool fr = ch < 8;
  const unsigned short* X = fr ? (Fb + ((size_t)b * TV + ch * 64) * H)
                               : (Tb + (size_t)b * TT * H);
  const float* ww = fr ? (aw_v + b * TV + ch * 64) : (aw_t + b * TT);
  float* out = fr ? (hv_sum + b * H) : (ht_sum + b * H);
  if (tid < 64) w[tid] = ww[tid];
  __syncthreads();
  const int j = tid * 2;
  float a0 = 0.f, a1 = 0.f;
  for (int t = 0; t < 64; ++t) {
    unsigned u = *(const unsigned*)(X + (size_t)t * H + j);
    float wt = w[t];
    a0 += wt * __uint_as_float(u << 16);
    a1 += wt * __uint_as_float(u & 0xffff0000u);
  }
  atomicAdd(&out[j], a0);
  atomicAdd(&out[j + 1], a1);
}

// ---- 5) gate scores from mv1'/mt1' (CB segs 2,3) -------------------------
// grid 128: i<64 -> mv row b=i; else mt row b=i-64. block 256.
__global__ void k_gate(const float* __restrict__ CB, const float* __restrict__ wbs,
                       const float* __restrict__ bbv, const float* __restrict__ bbt,
                       const float* __restrict__ wb, float* __restrict__ sArr) {
  __shared__ float red[4];
  const int i = blockIdx.x, tid = threadIdx.x;
  const bool fr = i < BB;
  const int b = fr ? i : i - BB;
  const float* m1 = CB + (size_t)(fr ? 2 : 3) * BB * H + (size_t)b * H;
  const float* b2 = fr ? bbv : bbt;
  float sp = 0.f;
#pragma unroll
  for (int jj = 0; jj < 2; ++jj) {
    int j = tid + jj * 256;
    float g = m1[j] + wbs[(size_t)b * H + j] + b2[j];
    sp += fast_tanh(g) * wb[j];
  }
  for (int d = 32; d; d >>= 1) sp += __shfl_xor(sp, d);
  if ((tid & 63) == 0) red[tid >> 6] = sp;
  __syncthreads();
  if (tid == 0) sArr[i] = red[0] + red[1] + red[2] + red[3];
}

// ---- 6) beta softmax + output (folds bve/bqe) ----------------------------
__global__ void k_final2(const float* __restrict__ sArr, const float* __restrict__ hwhh,
                         const float* __restrict__ bh,
                         const float* __restrict__ hv2, const float* __restrict__ ht2,
                         const float* __restrict__ bve, const float* __restrict__ bqe,
                         float* __restrict__ out) {
  __shared__ float red[4];
  const int b = blockIdx.x, tid = threadIdx.x;
  float v = (tid < 2 * BB) ? sArr[tid] : -1e30f;
  float mx = v;
  for (int d = 32; d; d >>= 1) mx = fmaxf(mx, __shfl_xor(mx, d));
  if ((tid & 63) == 0) red[tid >> 6] = mx;
  __syncthreads();
  mx = fmaxf(fmaxf(red[0], red[1]), fmaxf(red[2], red[3]));
  __syncthreads();
  float e = (tid < 2 * BB) ? __expf(v - mx) : 0.f;
  for (int d = 32; d; d >>= 1) e += __shfl_xor(e, d);
  if ((tid & 63) == 0) red[tid >> 6] = e;
  __syncthreads();
  const float Z = red[0] + red[1] + red[2] + red[3];
  const float beta0 = __expf(sArr[0] - mx) / Z;
  const float beta1 = __expf(sArr[1] - mx) / Z;
#pragma unroll
  for (int jj = 0; jj < 2; ++jj) {
    int j = tid + jj * 256;
    float x = hwhh[(size_t)b * H + j] + bh[j]
            + beta0 * (hv2[(size_t)b * H + j] + bve[j])
            + beta1 * (ht2[(size_t)b * H + j] + bqe[j]);
    out[(size_t)b * H + j] = fast_tanh(x);
  }
}

// ---- launch --------------------------------------------------------------

extern "C" void kernel_launch(void* const* d_in, const int* in_sizes, int n_in,
                              void* d_out, int out_size, void* d_ws, size_t ws_size,
                              hipStream_t stream) {
  const float* h    = (const float*)d_in[0];
  const float* F    = (const float*)d_in[1];
  const float* Txt  = (const float*)d_in[2];
  const float* Wav  = (const float*)d_in[3];
  const float* Wat  = (const float*)d_in[4];
  const float* Uav  = (const float*)d_in[5];
  const float* Uat  = (const float*)d_in[6];
  const float* Vav  = (const float*)d_in[7];
  const float* Vat  = (const float*)d_in[8];
  const float* bav  = (const float*)d_in[9];
  const float* bat  = (const float*)d_in[10];
  const float* Whh  = (const float*)d_in[11];
  const float* bh   = (const float*)d_in[12];
  const float* Wve  = (const float*)d_in[13];
  const float* bve  = (const float*)d_in[14];
  const float* Wqe  = (const float*)d_in[15];
  const float* bqe  = (const float*)d_in[16];
  const float* Wb   = (const float*)d_in[17];
  const float* Vbv  = (const float*)d_in[18];
  const float* Vbt  = (const float*)d_in[19];
  const float* bbv  = (const float*)d_in[20];
  const float* bbt  = (const float*)d_in[21];
  const float* wb   = (const float*)d_in[22];
  float* out = (float*)d_out;

  char* ws = (char*)d_ws;
  size_t off = 0;
  auto alloc = [&](size_t bytes) -> void* {
    void* p = ws + off;
    off += (bytes + 255) & ~(size_t)255;
    return p;
  };
  // zero-init region contiguous: score_v, score_t, hv_sum, ht_sum
  float* score_v = (float*)alloc((size_t)BB * TV * 4);   // 131072 B
  float* score_t = (float*)alloc((size_t)BB * TT * 4);   //  16384 B
  float* hv_sum  = (float*)alloc((size_t)BB * H * 4);    // 131072 B
  float* ht_sum  = (float*)alloc((size_t)BB * H * 4);    // 131072 B
  unsigned short* Wbf = (unsigned short*)alloc((size_t)10 * H * H * 2);  // 5.24 MB
  unsigned short* Fb  = (unsigned short*)alloc((size_t)BB * TV * H * 2); // 33.5 MB
  unsigned short* Tb  = (unsigned short*)alloc((size_t)BB * TT * H * 2); // 4.2 MB
  unsigned short* hb  = (unsigned short*)alloc((size_t)BB * H * 2);
  unsigned short* hvhtb = (unsigned short*)alloc((size_t)2 * BB * H * 2);
  float* CA   = (float*)alloc((size_t)4 * BB * H * 4);   // uv|ut|wbs|hwhh
  float* CB   = (float*)alloc((size_t)4 * BB * H * 4);   // hv2'|ht2'|mv1'|mt1'
  float* sArr = (float*)alloc((size_t)2 * BB * 4);

  float* uv   = CA;
  float* ut   = CA + (size_t)BB * H;
  float* wbs  = CA + (size_t)2 * BB * H;
  float* hwhh = CA + (size_t)3 * BB * H;

  hipMemsetAsync(score_v, 0, (size_t)(BB * TV + BB * TT + 2 * BB * H) * 4, stream);

  const size_t NTOT = (size_t)BB * (TV + TT + 1) * H;
  k_conv<<<dim3(NTOT / 8 / 256), 256, 0, stream>>>(F, Txt, h, Fb, Tb, hb);
  k_prep_w<<<dim3(8, 8, 10), 256, 0, stream>>>(Wav, Wat, Uav, Uat, Wb, Whh,
                                               Wve, Wqe, Vbv, Vbt, Wbf);
  // phase A: h @ [Uav|Uat|Wb|Whh] -> uv(+bav), ut(+bat), wbs, hwhh
  k_gemm64<<<dim3(8, 4), 256, 0, stream>>>(hb, nullptr, Wbf + (size_t)2 * H * H,
                                           CA, bav, bat, 0);
  k_score<9><<<dim3(BB * TV / 128, 4), 256, 0, stream>>>(Fb, Wbf, uv, Vav, score_v);
  k_score<6><<<dim3(BB * TT / 128, 4), 256, 0, stream>>>(Tb, Wbf + (size_t)H * H, ut, Vat, score_t);
  k_softmax<<<128, 256, 0, stream>>>(score_v, score_t);
  k_wsum<<<dim3(64, 9), 256, 0, stream>>>(Fb, Tb, score_v, score_t, hv_sum, ht_sum);
  k_conv2<<<dim3(2 * BB * H / 8 / 256), 256, 0, stream>>>(hv_sum, hvhtb);
  // phase B: {hv,ht} @ {Wve^T, Wqe^T, Vbv, Vbt} -> hv2', ht2', mv1', mt1'
  k_gemm64<<<dim3(8, 4), 256, 0, stream>>>(hvhtb, hvhtb + (size_t)BB * H,
                                           Wbf + (size_t)6 * H * H, CB,
                                           nullptr, nullptr, 1);
  k_gate<<<128, 256, 0, stream>>>(CB, wbs, bbv, bbt, wb, sArr);
  k_final2<<<64, 256, 0, stream>>>(sArr, hwhh, bh, CB, CB + (size_t)BB * H,
                                   bve, bqe, out);
}

// Round 4
// 223.347 us; speedup vs baseline: 1.4150x; 1.0514x over previous
//
#include <hip/hip_runtime.h>
#include <stdint.h>
#include <stddef.h>

#define H  512
#define BB 64
#define TV 512
#define TT 64

typedef short s8v __attribute__((ext_vector_type(8)));   // 8 bf16 (4 VGPRs)
typedef float f4v __attribute__((ext_vector_type(4)));   // MFMA accumulator

// ---- helpers -------------------------------------------------------------

__device__ inline unsigned short f2bf(float f) {
  unsigned int u = __float_as_uint(f);
  u = (u + 0x7fffu + ((u >> 16) & 1u)) >> 16;   // RNE
  return (unsigned short)u;
}

__device__ inline unsigned int pk2bf(float lo, float hi) {
  unsigned int a = __float_as_uint(lo);
  a = (a + 0x7fffu + ((a >> 16) & 1u)) >> 16;
  unsigned int b = __float_as_uint(hi);
  b = (b + 0x7fffu + ((b >> 16) & 1u)) & 0xffff0000u;
  return a | b;
}

__device__ inline float fast_tanh(float x) {
  x = fminf(15.f, fmaxf(-15.f, x));
  float e = __expf(2.f * x);
  return (e - 1.f) * __builtin_amdgcn_rcpf(e + 1.f);
}

// async global->LDS, 16 bytes per lane (global_load_lds_dwordx4)
__device__ inline void gld16(const unsigned short* g, unsigned short* l) {
  __builtin_amdgcn_global_load_lds(
      (const __attribute__((address_space(1))) unsigned int*)g,
      (__attribute__((address_space(3))) unsigned int*)l, 16, 0, 0);
}

// ---- 1) fused prep: convert F/Txt/h -> bf16, 10 weights -> bf16 ----------
// 1D grid. Blocks [0,8192): F conv; [8192,9216): Txt; [9216,9232): h;
// [9232,9872): weight z=(bx-9232)>>6, 64x64 tile (bx-9232)&63.
// z: 0 Wav^T 1 Wat^T 2 Uav^T 3 Uat^T 4 Wb^T 5 Whh^T 6 Wve cvt 7 Wqe cvt
//    8 Vbv^T 9 Vbt^T
__global__ void k_prep(const float* __restrict__ F, const float* __restrict__ Txt,
                       const float* __restrict__ h,
                       const float* __restrict__ Wav, const float* __restrict__ Wat,
                       const float* __restrict__ Uav, const float* __restrict__ Uat,
                       const float* __restrict__ Wb,  const float* __restrict__ Whh,
                       const float* __restrict__ Wve, const float* __restrict__ Wqe,
                       const float* __restrict__ Vbv, const float* __restrict__ Vbt,
                       unsigned short* __restrict__ Fb, unsigned short* __restrict__ Tb,
                       unsigned short* __restrict__ hb, unsigned short* __restrict__ Wbf) {
  __shared__ float tile[64][65];
  const int bx = blockIdx.x, tid = threadIdx.x;
  if (bx < 9232) {   // conversion region: 2048 elems per block
    const float* src; unsigned short* dst; size_t base;
    if (bx < 8192)      { base = (size_t)bx * 2048;          src = F;   dst = Fb; }
    else if (bx < 9216) { base = (size_t)(bx - 8192) * 2048; src = Txt; dst = Tb; }
    else                { base = (size_t)(bx - 9216) * 2048; src = h;   dst = hb; }
    size_t i = base + (size_t)tid * 8;
    float4 f0 = *(const float4*)(src + i);
    float4 f1 = *(const float4*)(src + i + 4);
    uint4 p;
    p.x = pk2bf(f0.x, f0.y); p.y = pk2bf(f0.z, f0.w);
    p.z = pk2bf(f1.x, f1.y); p.w = pk2bf(f1.z, f1.w);
    *(uint4*)(dst + i) = p;
    return;
  }
  const int z = (bx - 9232) >> 6;
  const int t = (bx - 9232) & 63;
  const int k0 = (t >> 3) * 64, j0 = (t & 7) * 64;
  const float* src =
      (z == 0) ? Wav : (z == 1) ? Wat : (z == 2) ? Uav : (z == 3) ? Uat :
      (z == 4) ? Wb  : (z == 5) ? Whh : (z == 6) ? Wve : (z == 7) ? Wqe :
      (z == 8) ? Vbv : Vbt;
  unsigned short* dst = Wbf + (size_t)z * H * H;
  if (z == 6 || z == 7) {          // straight convert
    for (int i = 0; i < 16; ++i) {
      int e = tid + i * 256; int r = e >> 6, c = e & 63;
      dst[(size_t)(k0 + r) * H + j0 + c] = f2bf(src[(size_t)(k0 + r) * H + j0 + c]);
    }
    return;
  }
  for (int i = 0; i < 16; ++i) {
    int e = tid + i * 256; int r = e >> 6, c = e & 63;
    tile[r][c] = src[(size_t)(k0 + r) * H + j0 + c];
  }
  __syncthreads();
  for (int i = 0; i < 16; ++i) {
    int e = tid + i * 256; int r = e >> 6, c = e & 63;
    dst[(size_t)(j0 + r) * H + k0 + c] = f2bf(tile[c][r]);
  }
}

// ---- 2) phase-A GEMM: CA[seg][64][512] = hb @ Wbf[2+seg]^T ---------------
// seg 0 uv(+bav) 1 ut(+bat) 2 wbs 3 hwhh.  grid (8,4) block 256.
__global__ __launch_bounds__(256)
void k_gemmA(const unsigned short* __restrict__ A0, const unsigned short* __restrict__ Bt,
             float* __restrict__ C,
             const float* __restrict__ bias0, const float* __restrict__ bias1) {
  __shared__ unsigned short As[64 * 32];
  __shared__ unsigned short Bs[64 * 32];
  const int tid = threadIdx.x;
  const int n0 = blockIdx.x * 64;
  const int seg = blockIdx.y;
  const unsigned short* B = Bt + (size_t)seg * H * H;

  const int r = tid >> 2, c = (tid & 3) * 8;
  const unsigned short* Ag = A0 + (size_t)r * H + c;
  const unsigned short* Bg = B + (size_t)(n0 + r) * H + c;
  unsigned short* Al = &As[tid * 8];
  unsigned short* Bl = &Bs[tid * 8];

  const int wv = tid >> 6, ln = tid & 63;
  const int quad = ln >> 4, l16 = ln & 15;
  const int wm = (wv >> 1) * 32, wn = (wv & 1) * 32;

  f4v acc[2][2] = {};
  for (int k0 = 0; k0 < H; k0 += 32) {
    __syncthreads();
    gld16(Ag + k0, Al);
    gld16(Bg + k0, Bl);
    __syncthreads();
    s8v afr[2], bfr[2];
#pragma unroll
    for (int mi = 0; mi < 2; ++mi)
      afr[mi] = *(const s8v*)&As[(wm + mi * 16 + l16) * 32 + quad * 8];
#pragma unroll
    for (int ni = 0; ni < 2; ++ni)
      bfr[ni] = *(const s8v*)&Bs[(wn + ni * 16 + l16) * 32 + quad * 8];
#pragma unroll
    for (int mi = 0; mi < 2; ++mi)
#pragma unroll
      for (int ni = 0; ni < 2; ++ni)
        acc[mi][ni] = __builtin_amdgcn_mfma_f32_16x16x32_bf16(afr[mi], bfr[ni], acc[mi][ni], 0, 0, 0);
  }

  const float* bias = (seg == 0) ? bias0 : (seg == 1) ? bias1 : nullptr;
  float* Cs = C + (size_t)seg * BB * H;
#pragma unroll
  for (int mi = 0; mi < 2; ++mi)
#pragma unroll
    for (int ni = 0; ni < 2; ++ni)
#pragma unroll
      for (int rr = 0; rr < 4; ++rr) {
        const int row = wm + mi * 16 + quad * 4 + rr;
        const int j = n0 + wn + ni * 16 + l16;
        float v = acc[mi][ni][rr];
        if (bias) v += bias[j];
        Cs[(size_t)row * H + j] = v;
      }
}

// ---- 3) fused score GEMM, frames+text in one launch ----------------------
// grid (288, 4): bx<256 frames (m0=bx*128, LOGT=9), else text (m0=(bx-256)*128,
// LOGT=6). score pre-zeroed (atomicAdd partials over 4 n-tiles).
__global__ __launch_bounds__(256)
void k_score(const unsigned short* __restrict__ Fb, const unsigned short* __restrict__ Tb,
             const unsigned short* __restrict__ Wbf,
             const float* __restrict__ uv, const float* __restrict__ ut,
             const float* __restrict__ Vav, const float* __restrict__ Vat,
             float* __restrict__ score_v, float* __restrict__ score_t) {
  __shared__ unsigned short As[128 * 32];
  __shared__ unsigned short Bs[128 * 32];
  const int tid = threadIdx.x;
  const int bx = blockIdx.x;
  const bool fr = bx < 256;
  const int m0 = (fr ? bx : bx - 256) * 128;
  const int n0 = blockIdx.y * 128;
  const int logT = fr ? 9 : 6;
  const unsigned short* A = fr ? Fb : Tb;
  const unsigned short* Bt = fr ? Wbf : (Wbf + (size_t)H * H);
  const float* uvw = fr ? uv : ut;
  const float* V = fr ? Vav : Vat;
  float* score = fr ? score_v : score_t;

  const int wv = tid >> 6, ln = tid & 63;
  const int quad = ln >> 4, l16 = ln & 15;
  const int wm = (wv >> 1) * 64, wn = (wv & 1) * 64;

  const int s0 = wv * 128 + ln;
  const int s1 = s0 + 64;
  const int r0 = s0 >> 2, c0 = (s0 & 3) * 8;
  const int r1 = s1 >> 2, c1 = (s1 & 3) * 8;

  const unsigned short* Ag0 = A + (size_t)(m0 + r0) * H + c0;
  const unsigned short* Ag1 = A + (size_t)(m0 + r1) * H + c1;
  const unsigned short* Bg0 = Bt + (size_t)(n0 + r0) * H + c0;
  const unsigned short* Bg1 = Bt + (size_t)(n0 + r1) * H + c1;
  unsigned short* Al0 = &As[s0 * 8];
  unsigned short* Al1 = &As[s1 * 8];
  unsigned short* Bl0 = &Bs[s0 * 8];
  unsigned short* Bl1 = &Bs[s1 * 8];

  f4v acc[4][4] = {};

  for (int k0 = 0; k0 < H; k0 += 32) {
    __syncthreads();
    gld16(Ag0 + k0, Al0);
    gld16(Ag1 + k0, Al1);
    gld16(Bg0 + k0, Bl0);
    gld16(Bg1 + k0, Bl1);
    __syncthreads();
    s8v afr[4], bfr[4];
#pragma unroll
    for (int mi = 0; mi < 4; ++mi)
      afr[mi] = *(const s8v*)&As[(wm + mi * 16 + l16) * 32 + quad * 8];
#pragma unroll
    for (int ni = 0; ni < 4; ++ni)
      bfr[ni] = *(const s8v*)&Bs[(wn + ni * 16 + l16) * 32 + quad * 8];
#pragma unroll
    for (int mi = 0; mi < 4; ++mi)
#pragma unroll
      for (int ni = 0; ni < 4; ++ni)
        acc[mi][ni] = __builtin_amdgcn_mfma_f32_16x16x32_bf16(afr[mi], bfr[ni], acc[mi][ni], 0, 0, 0);
  }

  int jj[4]; float vv[4];
#pragma unroll
  for (int ni = 0; ni < 4; ++ni) {
    jj[ni] = n0 + wn + ni * 16 + l16;
    vv[ni] = V[jj[ni]];
  }
  const int tmask = (1 << logT) - 1;
#pragma unroll
  for (int mi = 0; mi < 4; ++mi) {
    const int mrow0 = m0 + wm + mi * 16;
    const int bidx = mrow0 >> logT;
    const float* up = uvw + (size_t)bidx * H;
    float uu[4];
#pragma unroll
    for (int ni = 0; ni < 4; ++ni) uu[ni] = up[jj[ni]];
#pragma unroll
    for (int r = 0; r < 4; ++r) {
      float sum = 0.f;
#pragma unroll
      for (int ni = 0; ni < 4; ++ni)
        sum += fast_tanh(acc[mi][ni][r] + uu[ni]) * vv[ni];
      sum += __shfl_xor(sum, 1);
      sum += __shfl_xor(sum, 2);
      sum += __shfl_xor(sum, 4);
      sum += __shfl_xor(sum, 8);
      if (l16 == 0) {
        const int mrow = mrow0 + quad * 4 + r;
        atomicAdd(&score[((size_t)bidx << logT) + (mrow & tmask)], sum);
      }
    }
  }
}

// ---- 4) fused softmax + weighted sum ------------------------------------
// grid (64, 9): ch<8 frames t-chunk of 64; ch==8 text. Each block recomputes
// its row's softmax stats (cheap), then accumulates its chunk via atomicAdd.
// hv_sum/ht_sum pre-zeroed.
__global__ void k_wsum(const unsigned short* __restrict__ Fb, const unsigned short* __restrict__ Tb,
                       const float* __restrict__ score_v, const float* __restrict__ score_t,
                       float* __restrict__ hv_sum, float* __restrict__ ht_sum) {
  __shared__ float w[64];
  __shared__ float red[4];
  const int b = blockIdx.x, ch = blockIdx.y, tid = threadIdx.x;
  const bool fr = ch < 8;
  const float* sc = fr ? (score_v + b * TV) : (score_t + b * TT);
  const int T = fr ? TV : TT;

  float v0 = (tid < T) ? sc[tid] : -1e30f;
  float v1 = fr ? sc[tid + 256] : -1e30f;
  float mx = fmaxf(v0, v1);
  for (int d = 32; d; d >>= 1) mx = fmaxf(mx, __shfl_xor(mx, d));
  if ((tid & 63) == 0) red[tid >> 6] = mx;
  __syncthreads();
  mx = fmaxf(fmaxf(red[0], red[1]), fmaxf(red[2], red[3]));
  __syncthreads();
  float e0 = (tid < T) ? __expf(v0 - mx) : 0.f;
  float e1 = fr ? __expf(v1 - mx) : 0.f;
  float se = e0 + e1;
  for (int d = 32; d; d >>= 1) se += __shfl_xor(se, d);
  if ((tid & 63) == 0) red[tid >> 6] = se;
  __syncthreads();
  const float inv = 1.f / (red[0] + red[1] + red[2] + red[3]);
  const int t0 = fr ? ch * 64 : 0;
  if (tid < 64) w[tid] = __expf(sc[t0 + tid] - mx) * inv;
  __syncthreads();

  const unsigned short* X = fr ? (Fb + ((size_t)b * TV + t0) * H)
                               : (Tb + (size_t)b * TT * H);
  float* out = fr ? (hv_sum + b * H) : (ht_sum + b * H);
  const int j = tid * 2;
  float a0 = 0.f, a1 = 0.f;
  for (int t = 0; t < 64; ++t) {
    unsigned u = *(const unsigned*)(X + (size_t)t * H + j);
    float wt = w[t];
    a0 += wt * __uint_as_float(u << 16);
    a1 += wt * __uint_as_float(u & 0xffff0000u);
  }
  atomicAdd(&out[j], a0);
  atomicAdd(&out[j + 1], a1);
}

// ---- 5) phase-B GEMM with in-kernel fp32->bf16 A staging -----------------
// CB[seg][64][512]: seg 0 hv@Wve^T, 1 ht@Wqe^T, 2 hv@Vbv, 3 ht@Vbt.
// A = hv_sum (seg even) / ht_sum (seg odd), contiguous fp32 [2*BB][H].
// grid (8,4), block 256.
__global__ __launch_bounds__(256)
void k_gemmB(const float* __restrict__ Afp, const unsigned short* __restrict__ Bt,
             float* __restrict__ C) {
  __shared__ unsigned short As[64 * 32];
  __shared__ unsigned short Bs[64 * 32];
  const int tid = threadIdx.x;
  const int n0 = blockIdx.x * 64;
  const int seg = blockIdx.y;
  const float* A = Afp + (size_t)((seg & 1) ? BB * H : 0);
  const unsigned short* B = Bt + (size_t)seg * H * H;

  const int r = tid >> 2, c = (tid & 3) * 8;
  const float* Ag = A + (size_t)r * H + c;
  const unsigned short* Bg = B + (size_t)(n0 + r) * H + c;
  unsigned short* Bl = &Bs[tid * 8];

  const int wv = tid >> 6, ln = tid & 63;
  const int quad = ln >> 4, l16 = ln & 15;
  const int wm = (wv >> 1) * 32, wn = (wv & 1) * 32;

  f4v acc[2][2] = {};
  for (int k0 = 0; k0 < H; k0 += 32) {
    __syncthreads();
    float4 f0 = *(const float4*)(Ag + k0);
    float4 f1 = *(const float4*)(Ag + k0 + 4);
    uint4 p;
    p.x = pk2bf(f0.x, f0.y); p.y = pk2bf(f0.z, f0.w);
    p.z = pk2bf(f1.x, f1.y); p.w = pk2bf(f1.z, f1.w);
    *(uint4*)&As[tid * 8] = p;
    gld16(Bg + k0, Bl);
    __syncthreads();
    s8v afr[2], bfr[2];
#pragma unroll
    for (int mi = 0; mi < 2; ++mi)
      afr[mi] = *(const s8v*)&As[(wm + mi * 16 + l16) * 32 + quad * 8];
#pragma unroll
    for (int ni = 0; ni < 2; ++ni)
      bfr[ni] = *(const s8v*)&Bs[(wn + ni * 16 + l16) * 32 + quad * 8];
#pragma unroll
    for (int mi = 0; mi < 2; ++mi)
#pragma unroll
      for (int ni = 0; ni < 2; ++ni)
        acc[mi][ni] = __builtin_amdgcn_mfma_f32_16x16x32_bf16(afr[mi], bfr[ni], acc[mi][ni], 0, 0, 0);
  }

  float* Cs = C + (size_t)seg * BB * H;
#pragma unroll
  for (int mi = 0; mi < 2; ++mi)
#pragma unroll
    for (int ni = 0; ni < 2; ++ni)
#pragma unroll
      for (int rr = 0; rr < 4; ++rr) {
        const int row = wm + mi * 16 + quad * 4 + rr;
        const int j = n0 + wn + ni * 16 + l16;
        Cs[(size_t)row * H + j] = acc[mi][ni][rr];
      }
}

// ---- 6) gate scores from mv1'/mt1' (CB segs 2,3) -------------------------
__global__ void k_gate(const float* __restrict__ CB, const float* __restrict__ wbs,
                       const float* __restrict__ bbv, const float* __restrict__ bbt,
                       const float* __restrict__ wb, float* __restrict__ sArr) {
  __shared__ float red[4];
  const int i = blockIdx.x, tid = threadIdx.x;
  const bool fr = i < BB;
  const int b = fr ? i : i - BB;
  const float* m1 = CB + (size_t)(fr ? 2 : 3) * BB * H + (size_t)b * H;
  const float* b2 = fr ? bbv : bbt;
  float sp = 0.f;
#pragma unroll
  for (int jj = 0; jj < 2; ++jj) {
    int j = tid + jj * 256;
    float g = m1[j] + wbs[(size_t)b * H + j] + b2[j];
    sp += fast_tanh(g) * wb[j];
  }
  for (int d = 32; d; d >>= 1) sp += __shfl_xor(sp, d);
  if ((tid & 63) == 0) red[tid >> 6] = sp;
  __syncthreads();
  if (tid == 0) sArr[i] = red[0] + red[1] + red[2] + red[3];
}

// ---- 7) beta softmax + output (folds bve/bqe) ----------------------------
__global__ void k_final2(const float* __restrict__ sArr, const float* __restrict__ hwhh,
                         const float* __restrict__ bh,
                         const float* __restrict__ hv2, const float* __restrict__ ht2,
                         const float* __restrict__ bve, const float* __restrict__ bqe,
                         float* __restrict__ out) {
  __shared__ float red[4];
  const int b = blockIdx.x, tid = threadIdx.x;
  float v = (tid < 2 * BB) ? sArr[tid] : -1e30f;
  float mx = v;
  for (int d = 32; d; d >>= 1) mx = fmaxf(mx, __shfl_xor(mx, d));
  if ((tid & 63) == 0) red[tid >> 6] = mx;
  __syncthreads();
  mx = fmaxf(fmaxf(red[0], red[1]), fmaxf(red[2], red[3]));
  __syncthreads();
  float e = (tid < 2 * BB) ? __expf(v - mx) : 0.f;
  for (int d = 32; d; d >>= 1) e += __shfl_xor(e, d);
  if ((tid & 63) == 0) red[tid >> 6] = e;
  __syncthreads();
  const float Z = red[0] + red[1] + red[2] + red[3];
  const float beta0 = __expf(sArr[0] - mx) / Z;
  const float beta1 = __expf(sArr[1] - mx) / Z;
#pragma unroll
  for (int jj = 0; jj < 2; ++jj) {
    int j = tid + jj * 256;
    float x = hwhh[(size_t)b * H + j] + bh[j]
            + beta0 * (hv2[(size_t)b * H + j] + bve[j])
            + beta1 * (ht2[(size_t)b * H + j] + bqe[j]);
    out[(size_t)b * H + j] = fast_tanh(x);
  }
}

// ---- launch --------------------------------------------------------------

extern "C" void kernel_launch(void* const* d_in, const int* in_sizes, int n_in,
                              void* d_out, int out_size, void* d_ws, size_t ws_size,
                              hipStream_t stream) {
  const float* h    = (const float*)d_in[0];
  const float* F    = (const float*)d_in[1];
  const float* Txt  = (const float*)d_in[2];
  const float* Wav  = (const float*)d_in[3];
  const float* Wat  = (const float*)d_in[4];
  const float* Uav  = (const float*)d_in[5];
  const float* Uat  = (const float*)d_in[6];
  const float* Vav  = (const float*)d_in[7];
  const float* Vat  = (const float*)d_in[8];
  const float* bav  = (const float*)d_in[9];
  const float* bat  = (const float*)d_in[10];
  const float* Whh  = (const float*)d_in[11];
  const float* bh   = (const float*)d_in[12];
  const float* Wve  = (const float*)d_in[13];
  const float* bve  = (const float*)d_in[14];
  const float* Wqe  = (const float*)d_in[15];
  const float* bqe  = (const float*)d_in[16];
  const float* Wb   = (const float*)d_in[17];
  const float* Vbv  = (const float*)d_in[18];
  const float* Vbt  = (const float*)d_in[19];
  const float* bbv  = (const float*)d_in[20];
  const float* bbt  = (const float*)d_in[21];
  const float* wb   = (const float*)d_in[22];
  float* out = (float*)d_out;

  char* ws = (char*)d_ws;
  size_t off = 0;
  auto alloc = [&](size_t bytes) -> void* {
    void* p = ws + off;
    off += (bytes + 255) & ~(size_t)255;
    return p;
  };
  // zero-init region contiguous: score_v, score_t, hv_sum, ht_sum
  float* score_v = (float*)alloc((size_t)BB * TV * 4);   // 131072 B
  float* score_t = (float*)alloc((size_t)BB * TT * 4);   //  16384 B
  float* hv_sum  = (float*)alloc((size_t)BB * H * 4);    // 131072 B
  float* ht_sum  = (float*)alloc((size_t)BB * H * 4);    // 131072 B (contiguous after hv)
  unsigned short* Wbf = (unsigned short*)alloc((size_t)10 * H * H * 2);  // 5.24 MB
  unsigned short* Fb  = (unsigned short*)alloc((size_t)BB * TV * H * 2); // 33.5 MB
  unsigned short* Tb  = (unsigned short*)alloc((size_t)BB * TT * H * 2); // 4.2 MB
  unsigned short* hb  = (unsigned short*)alloc((size_t)BB * H * 2);
  float* CA   = (float*)alloc((size_t)4 * BB * H * 4);   // uv|ut|wbs|hwhh
  float* CB   = (float*)alloc((size_t)4 * BB * H * 4);   // hv2'|ht2'|mv1'|mt1'
  float* sArr = (float*)alloc((size_t)2 * BB * 4);

  float* uv   = CA;
  float* ut   = CA + (size_t)BB * H;
  float* wbs  = CA + (size_t)2 * BB * H;
  float* hwhh = CA + (size_t)3 * BB * H;

  hipMemsetAsync(score_v, 0, (size_t)(BB * TV + BB * TT + 2 * BB * H) * 4, stream);

  k_prep<<<dim3(9872), 256, 0, stream>>>(F, Txt, h, Wav, Wat, Uav, Uat, Wb, Whh,
                                         Wve, Wqe, Vbv, Vbt, Fb, Tb, hb, Wbf);
  k_gemmA<<<dim3(8, 4), 256, 0, stream>>>(hb, Wbf + (size_t)2 * H * H, CA, bav, bat);
  k_score<<<dim3(288, 4), 256, 0, stream>>>(Fb, Tb, Wbf, uv, ut, Vav, Vat,
                                            score_v, score_t);
  k_wsum<<<dim3(64, 9), 256, 0, stream>>>(Fb, Tb, score_v, score_t, hv_sum, ht_sum);
  k_gemmB<<<dim3(8, 4), 256, 0, stream>>>(hv_sum, Wbf + (size_t)6 * H * H, CB);
  k_gate<<<128, 256, 0, stream>>>(CB, wbs, bbv, bbt, wb, sArr);
  k_final2<<<64, 256, 0, stream>>>(sArr, hwhh, bh, CB, CB + (size_t)BB * H,
                                   bve, bqe, out);
}